// Round 2
// baseline (879.368 us; speedup 1.0000x reference)
//
#include <hip/hip_runtime.h>
#include <hip/hip_bf16.h>
#include <cstdint>
#include <cstddef>

// ---------------------------------------------------------------------------
// ChildSumTreeLSTM, complete binary tree N=131071=2^17-1, dim 256.
// Per level L (count parents, children at L+1 already have local c,h):
//   A1[i]    = [ x_{s+i} | h_{2i} + h_{2i+1} ]           (count x 512, bf16)
//   A2[j]    = [ x_parent(j) | h_j ]                     (2count x 512, bf16)
//   FC       = f-GEMM(A2 @ [W_fx|W_fh]^T) fused epilogue:
//              f = sig(. + b_fx+b_fh); FC[p] = f_{2p} c_{2p} + f_{2p+1} c_{2p+1}
//   iou-GEMM:  A1 @ [W_ioux|W_iouh]^T, fused gates:
//              c = sig(i) tanh(u) + FC; h = sig(o) tanh(c)
// Leaf level: iou-GEMM with A = bf16(X_leaf), K=256 (ldb=512 skips W_iouh), FC=0.
// Workspace ~186 MB total (round-1 crash diagnosed as d_ws overrun at 672 MB).
// ---------------------------------------------------------------------------

typedef __bf16 bf16;
typedef bf16 bf16x8 __attribute__((ext_vector_type(8)));
typedef float f32x4 __attribute__((ext_vector_type(4)));

#define LEAF_START 65535
#define LEAF_COUNT 65536

__device__ __forceinline__ float sigf(float x) { return 1.0f / (1.0f + __expf(-x)); }
__device__ __forceinline__ float tanh_fast(float x) {
  return 1.0f - 2.0f / (__expf(2.0f * x) + 1.0f);
}

// Build concatenated bf16 weights + fused fp32 biases.
__global__ void prep_weights(const float* __restrict__ Wioux, const float* __restrict__ Wiouh,
                             const float* __restrict__ Wfx, const float* __restrict__ Wfh,
                             const float* __restrict__ bioux, const float* __restrict__ biouh,
                             const float* __restrict__ bfx, const float* __restrict__ bfh,
                             bf16* __restrict__ Wiou, bf16* __restrict__ Wf,
                             float* __restrict__ biou, float* __restrict__ bfc)
{
  const int el = blockIdx.x * 256 + threadIdx.x;   // 0 .. 524287
  if (el < 768 * 512) {
    const int r = el >> 9, c = el & 511;
    const float v = (c < 256) ? Wioux[r * 256 + c] : Wiouh[r * 256 + c - 256];
    Wiou[el] = (bf16)v;
  } else {
    const int e2 = el - 768 * 512;                 // 0 .. 131071
    const int r = e2 >> 9, c = e2 & 511;
    const float v = (c < 256) ? Wfx[r * 256 + c] : Wfh[r * 256 + c - 256];
    Wf[e2] = (bf16)v;
  }
  if (el < 768)       biou[el] = bioux[el] + biouh[el];
  else if (el < 1024) bfc[el - 768] = bfx[el - 768] + bfh[el - 768];
}

// Convert leaf rows of X (fp32) to bf16 into A1 (65536 x 256).
__global__ void leaf_convert(const float* __restrict__ X, bf16* __restrict__ A1)
{
  const int i = blockIdx.x * 256 + threadIdx.x;    // float4 quad index, exact grid
  const float4 v = ((const float4*)(X + (size_t)LEAF_START * 256))[i];
  union { ushort4 u; bf16 b[4]; } cv;
  cv.b[0] = (bf16)v.x; cv.b[1] = (bf16)v.y; cv.b[2] = (bf16)v.z; cv.b[3] = (bf16)v.w;
  ((ushort4*)A1)[i] = cv.u;
}

// Pack A1 ([x_p | hsum]) and A2 ([x_p | h_child]) for parents [p0,p1).
// ch0 = first child (level-local) row held in this A2 chunk.
__global__ __launch_bounds__(256) void pack_level(
    const float* __restrict__ X, const bf16* __restrict__ H,
    bf16* __restrict__ A1, bf16* __restrict__ A2,
    int s, int p0, int p1, int ch0)
{
  const int sub = threadIdx.x >> 6;
  const int i = p0 + blockIdx.x * 4 + sub;         // parent level-local index
  if (i >= p1) return;
  const int c4 = (threadIdx.x & 63) * 4;
  const float4 xv = *(const float4*)(X + (size_t)(s + i) * 256 + c4);
  union { ushort4 u; bf16 b[4]; } xb, h0, h1, hs;
  xb.b[0] = (bf16)xv.x; xb.b[1] = (bf16)xv.y; xb.b[2] = (bf16)xv.z; xb.b[3] = (bf16)xv.w;
  h0.u = *(const ushort4*)(H + (size_t)(2 * i) * 256 + c4);
  h1.u = *(const ushort4*)(H + (size_t)(2 * i + 1) * 256 + c4);
#pragma unroll
  for (int q = 0; q < 4; ++q) hs.b[q] = (bf16)((float)h0.b[q] + (float)h1.b[q]);
  bf16* a1 = A1 + (size_t)i * 512;
  *(ushort4*)(a1 + c4) = xb.u;
  *(ushort4*)(a1 + 256 + c4) = hs.u;
  bf16* a2 = A2 + (size_t)(2 * i - ch0) * 512;
  *(ushort4*)(a2 + c4) = xb.u;
  *(ushort4*)(a2 + 256 + c4) = h0.u;
  *(ushort4*)(a2 + 512 + c4) = xb.u;
  *(ushort4*)(a2 + 768 + c4) = h1.u;
}

// F = A2(M2 x 512) @ Wf(256 x 512)^T; fused: f=sig(F+bfc); FC[p]=f0*c0+f1*c1.
__global__ __launch_bounds__(256) void f_gemm(
    const bf16* __restrict__ A2, const bf16* __restrict__ Wf,
    const float* __restrict__ bfc, const bf16* __restrict__ Cc,
    float* __restrict__ FC, int M2, int ch0)
{
  __shared__ bf16 As[64][72];
  __shared__ bf16 Bs[64][72];
  const int t = threadIdx.x, wave = t >> 6, lane = t & 63;
  const int quad = lane >> 4, lc = lane & 15;
  const int mBase = blockIdx.y * 64, nBase = blockIdx.x * 64;
  f32x4 acc[4] = {};
  const int r0 = t >> 3, cc = (t & 7) * 8;
  for (int kt = 0; kt < 512; kt += 64) {
#pragma unroll
    for (int rr = 0; rr < 2; ++rr) {
      const int r = r0 + rr * 32;
      uint4 va = {0u, 0u, 0u, 0u};
      if (mBase + r < M2) va = *(const uint4*)(A2 + (size_t)(mBase + r) * 512 + kt + cc);
      *(uint4*)&As[r][cc] = va;
      const uint4 vb = *(const uint4*)(Wf + (size_t)(nBase + r) * 512 + kt + cc);
      *(uint4*)&Bs[r][cc] = vb;
    }
    __syncthreads();
#pragma unroll
    for (int kk = 0; kk < 64; kk += 32) {
      bf16x8 a = *(const bf16x8*)&As[wave * 16 + lc][kk + quad * 8];
#pragma unroll
      for (int nt = 0; nt < 4; ++nt) {
        bf16x8 b = *(const bf16x8*)&Bs[nt * 16 + lc][kk + quad * 8];
        acc[nt] = __builtin_amdgcn_mfma_f32_16x16x32_bf16(a, b, acc[nt], 0, 0, 0);
      }
    }
    __syncthreads();
  }
  const int rowBase = mBase + wave * 16 + quad * 4;
#pragma unroll
  for (int nt = 0; nt < 4; ++nt) {
    const int col = nBase + nt * 16 + lc;
    const float bv = bfc[col];
#pragma unroll
    for (int r = 0; r < 4; r += 2) {
      const int rc = rowBase + r;                  // even chunk-local child row
      if (rc < M2) {
        const int jg = ch0 + rc;                   // level-local child index (even)
        const float f0 = sigf(acc[nt][r]     + bv);
        const float f1 = sigf(acc[nt][r + 1] + bv);
        const float c0 = (float)Cc[(size_t)jg * 256 + col];
        const float c1 = (float)Cc[(size_t)(jg + 1) * 256 + col];
        FC[(size_t)(jg >> 1) * 256 + col] = f0 * c0 + f1 * c1;
      }
    }
  }
}

// IOU = A(M x K) @ Wiou(768 x 512, ldb=512)^T with i/o/u column tiles at
// stride 256 co-resident per block -> lane-local gates; writes c,h (and root out).
__global__ __launch_bounds__(256) void iou_gemm(
    const bf16* __restrict__ A, int lda, int K,
    const bf16* __restrict__ Wiou, const float* __restrict__ biou,
    const float* __restrict__ FC,
    bf16* __restrict__ Cst, bf16* __restrict__ H,
    float* __restrict__ out, int M, int isRoot)
{
  __shared__ bf16 As[64][72];
  __shared__ bf16 Bs[96][72];
  const int t = threadIdx.x, wave = t >> 6, lane = t & 63;
  const int quad = lane >> 4, lc = lane & 15;
  const int mBase = blockIdx.y * 64;
  const int chBase = blockIdx.x * 32;              // 32 channels per block
  f32x4 acc[2][3] = {};
  const int r0 = t >> 3, cc = (t & 7) * 8;
  for (int kt = 0; kt < K; kt += 64) {
#pragma unroll
    for (int rr = 0; rr < 2; ++rr) {
      const int r = r0 + rr * 32;
      uint4 va = {0u, 0u, 0u, 0u};
      if (mBase + r < M) va = *(const uint4*)(A + (size_t)(mBase + r) * lda + kt + cc);
      *(uint4*)&As[r][cc] = va;
    }
#pragma unroll
    for (int rr = 0; rr < 3; ++rr) {
      const int rb = r0 + rr * 32;                 // 0..95
      const int cgpart = rb >> 4;                  // 0..5 = cg*3+part
      const int cg = cgpart / 3, part = cgpart % 3;
      const int brow = part * 256 + chBase + cg * 16 + (rb & 15);
      const uint4 vb = *(const uint4*)(Wiou + (size_t)brow * 512 + kt + cc);
      *(uint4*)&Bs[rb][cc] = vb;
    }
    __syncthreads();
#pragma unroll
    for (int kk = 0; kk < 64; kk += 32) {
      bf16x8 a = *(const bf16x8*)&As[wave * 16 + lc][kk + quad * 8];
#pragma unroll
      for (int cg = 0; cg < 2; ++cg)
#pragma unroll
        for (int part = 0; part < 3; ++part) {
          bf16x8 b = *(const bf16x8*)&Bs[(cg * 3 + part) * 16 + lc][kk + quad * 8];
          acc[cg][part] = __builtin_amdgcn_mfma_f32_16x16x32_bf16(a, b, acc[cg][part], 0, 0, 0);
        }
    }
    __syncthreads();
  }
#pragma unroll
  for (int cg = 0; cg < 2; ++cg) {
    const int ch = chBase + cg * 16 + lc;
    const float bi = biou[ch], bo = biou[256 + ch], bu = biou[512 + ch];
#pragma unroll
    for (int r = 0; r < 4; ++r) {
      const int row = mBase + wave * 16 + quad * 4 + r;
      if (row < M) {
        const float iv = acc[cg][0][r] + bi;
        const float ov = acc[cg][1][r] + bo;
        const float uv = acc[cg][2][r] + bu;
        const float fc = FC ? FC[(size_t)row * 256 + ch] : 0.0f;
        const float cv = sigf(iv) * tanh_fast(uv) + fc;
        const float hv = sigf(ov) * tanh_fast(cv);
        Cst[(size_t)row * 256 + ch] = (bf16)cv;
        H[(size_t)row * 256 + ch] = (bf16)hv;
        if (isRoot && row == 0) { out[ch] = cv; out[256 + ch] = hv; }
      }
    }
  }
}

extern "C" void kernel_launch(void* const* d_in, const int* in_sizes, int n_in,
                              void* d_out, int out_size, void* d_ws, size_t ws_size,
                              hipStream_t stream)
{
  const float* X      = (const float*)d_in[0];
  const float* Wioux  = (const float*)d_in[1];
  const float* bioux  = (const float*)d_in[2];
  const float* Wiouh  = (const float*)d_in[3];
  const float* biouh  = (const float*)d_in[4];
  const float* Wfx    = (const float*)d_in[5];
  const float* bfx    = (const float*)d_in[6];
  const float* Wfh    = (const float*)d_in[7];
  const float* bfh    = (const float*)d_in[8];
  float* out = (float*)d_out;
  (void)in_sizes; (void)n_in; (void)out_size; (void)ws_size;

  // workspace layout: ~185.6 MB total
  char* ws = (char*)d_ws;
  size_t off = 0;
  auto alloc = [&](size_t bytes) -> char* {
    char* p = ws + off;
    off += (bytes + 255) & ~(size_t)255;
    return p;
  };
  bf16*  Wiou   = (bf16*)alloc((size_t)768 * 512 * 2);   // [W_ioux | W_iouh]
  bf16*  Wf     = (bf16*)alloc((size_t)256 * 512 * 2);   // [W_fx | W_fh]
  float* biou   = (float*)alloc(768 * 4);
  float* bfc    = (float*)alloc(256 * 4);
  bf16*  A1     = (bf16*)alloc((size_t)32768 * 512 * 2); // = 65536*256*2 (leaf)
  bf16*  A2     = (bf16*)alloc((size_t)32768 * 512 * 2); // chunk-capped
  float* FC     = (float*)alloc((size_t)32768 * 256 * 4);
  bf16*  H      = (bf16*)alloc((size_t)65536 * 256 * 2); // level-local child h
  bf16*  Cbig   = (bf16*)alloc((size_t)65536 * 256 * 2); // c for even levels+leaf
  bf16*  Csmall = (bf16*)alloc((size_t)32768 * 256 * 2); // c for odd levels

  prep_weights<<<2048, 256, 0, stream>>>(Wioux, Wiouh, Wfx, Wfh,
                                         bioux, biouh, bfx, bfh,
                                         Wiou, Wf, biou, bfc);

  // Leaf level (stored at level-local rows 0..65535 of H / Cbig)
  leaf_convert<<<16384, 256, 0, stream>>>(X, A1);
  iou_gemm<<<dim3(8, 1024), 256, 0, stream>>>(A1, 256, 256, Wiou, biou, nullptr,
                                              Cbig, H, out, LEAF_COUNT, 0);

  // Internal levels, bottom-up
  for (int lvl = 15; lvl >= 0; --lvl) {
    const int count = 1 << lvl;
    const int s = count - 1;
    bf16* Ccur   = (lvl & 1) ? Csmall : Cbig;
    bf16* Cchild = (lvl & 1) ? Cbig   : Csmall;
    const int nchunk = (2 * count > 32768) ? 2 : 1;   // only lvl 15
    const int half = count / nchunk;
    for (int ck = 0; ck < nchunk; ++ck) {
      const int p0 = ck * half, p1 = p0 + half;
      const int ch0 = 2 * p0;
      const int M2 = 2 * half;
      pack_level<<<(p1 - p0 + 3) / 4, 256, 0, stream>>>(X, H, A1, A2, s, p0, p1, ch0);
      f_gemm<<<dim3(4, (M2 + 63) / 64), 256, 0, stream>>>(A2, Wf, bfc, Cchild, FC, M2, ch0);
    }
    iou_gemm<<<dim3(8, (count + 63) / 64), 256, 0, stream>>>(
        A1, 512, 512, Wiou, biou, FC, Ccur, H, out, count, lvl == 0);
  }
}